// Round 5
// baseline (1015.072 us; speedup 1.0000x reference)
//
#include <hip/hip_runtime.h>

typedef unsigned int uint;
typedef __attribute__((ext_vector_type(8))) short bf16x8;
typedef __attribute__((ext_vector_type(4))) float f32x4;

__device__ __forceinline__ float b2f(ushort h) { return __uint_as_float(((uint)h) << 16); }
__device__ __forceinline__ ushort f2b(float f) {
    uint u = __float_as_uint(f);
    return (ushort)((u + 0x7fffu + ((u >> 16) & 1u)) >> 16);
}

#define HBINS 4096

// ================= fused prep: f2b(x) | wtrans | partitioned hist+rw =================
// grid: [0,Gf2b) f2b ; [Gf2b, Gf2b+256) wtrans ; [Gf2b+256, Gf2b+256+NB) hist
__global__ __launch_bounds__(1024) void prep_k(
    const float* __restrict__ x, ushort* __restrict__ xb, long n8,
    const float* __restrict__ W1, const float* __restrict__ W2,
    const float* __restrict__ W3, const float* __restrict__ b3,
    ushort* __restrict__ Wt1, ushort* __restrict__ Wt2,
    ushort* __restrict__ Wt3, float* __restrict__ b3p, int NC,
    const int* __restrict__ d1, const int* __restrict__ d2, const int* __restrict__ d3,
    const float* __restrict__ ew1, const float* __restrict__ ew2,
    int E1, int E2, int E3, int n1, int n2, int NT,
    int* __restrict__ cnt, float* __restrict__ rw, int Gf2b) {
    __shared__ int bins[HBINS];
    __shared__ float rws[HBINS];
    int b = blockIdx.x;
    if (b < Gf2b) {
        long i = (long)b * 1024 + threadIdx.x;
        long st = (long)Gf2b * 1024;
        for (; i < n8; i += st) {
            float4 a = reinterpret_cast<const float4*>(x)[i * 2];
            float4 c = reinterpret_cast<const float4*>(x)[i * 2 + 1];
            ushort4 o0, o1;
            o0.x = f2b(a.x); o0.y = f2b(a.y); o0.z = f2b(a.z); o0.w = f2b(a.w);
            o1.x = f2b(c.x); o1.y = f2b(c.y); o1.z = f2b(c.z); o1.w = f2b(c.w);
            reinterpret_cast<ushort4*>(xb)[i * 2] = o0;
            reinterpret_cast<ushort4*>(xb)[i * 2 + 1] = o1;
        }
        return;
    }
    b -= Gf2b;
    if (b < 256) {
        int k = b;
        int t = threadIdx.x;
        if (t < 256) {
            Wt1[(long)t * 256 + k] = f2b(W1[(long)k * 256 + t]);
        } else if (t < 512) {
            int n = t - 256;
            Wt2[(long)n * 256 + k] = f2b(W2[(long)k * 256 + n]);
        } else if (t < 640) {
            int n = t - 512;
            float v = (n < NC) ? W3[(long)k * NC + n] : 0.f;
            Wt3[(long)n * 256 + k] = f2b(v);
            if (k == 0) b3p[n] = (n < NC) ? b3[n] : 0.f;
        }
        return;
    }
    b -= 256;
    // ---- partitioned histogram: this block owns bins [b*HBINS, b*HBINS+HBINS) ----
    const int base = b * HBINS;
    for (int i = threadIdx.x; i < HBINS; i += 1024) { bins[i] = 0; rws[i] = 0.f; }
    __syncthreads();
    {   // segment 1: offset 0, weights ew1
        int n4 = E1 >> 2;
        const int4* dd = (const int4*)d1;
        for (int i = threadIdx.x; i < n4; i += 1024) {
            int4 v = dd[i];
            int dv[4] = {v.x, v.y, v.z, v.w};
            #pragma unroll
            for (int u = 0; u < 4; ++u) {
                int r = dv[u] - base;
                if ((uint)r < HBINS) { atomicAdd(&bins[r], 1); atomicAdd(&rws[r], ew1[i * 4 + u]); }
            }
        }
        for (int i = n4 * 4 + threadIdx.x; i < E1; i += 1024) {
            int r = d1[i] - base;
            if ((uint)r < HBINS) { atomicAdd(&bins[r], 1); atomicAdd(&rws[r], ew1[i]); }
        }
    }
    {   // segment 2: offset n1, weights ew2
        int n4 = E2 >> 2;
        const int4* dd = (const int4*)d2;
        for (int i = threadIdx.x; i < n4; i += 1024) {
            int4 v = dd[i];
            int dv[4] = {v.x, v.y, v.z, v.w};
            #pragma unroll
            for (int u = 0; u < 4; ++u) {
                int r = n1 + dv[u] - base;
                if ((uint)r < HBINS) { atomicAdd(&bins[r], 1); atomicAdd(&rws[r], ew2[i * 4 + u]); }
            }
        }
        for (int i = n4 * 4 + threadIdx.x; i < E2; i += 1024) {
            int r = n1 + d2[i] - base;
            if ((uint)r < HBINS) { atomicAdd(&bins[r], 1); atomicAdd(&rws[r], ew2[i]); }
        }
    }
    {   // segment 3: offset n1+n2, no weights
        int n4 = E3 >> 2;
        const int4* dd = (const int4*)d3;
        for (int i = threadIdx.x; i < n4; i += 1024) {
            int4 v = dd[i];
            int dv[4] = {v.x, v.y, v.z, v.w};
            #pragma unroll
            for (int u = 0; u < 4; ++u) {
                int r = n1 + n2 + dv[u] - base;
                if ((uint)r < HBINS) atomicAdd(&bins[r], 1);
            }
        }
        for (int i = n4 * 4 + threadIdx.x; i < E3; i += 1024) {
            int r = n1 + n2 + d3[i] - base;
            if ((uint)r < HBINS) atomicAdd(&bins[r], 1);
        }
    }
    __syncthreads();
    for (int i = threadIdx.x; i < HBINS; i += 1024) {
        int g = base + i;
        if (g < NT) {
            cnt[g] = bins[i];
            if (g < n1 + n2) rw[g] = rws[i];
        }
    }
}

// ---- 3-phase parallel exclusive scan ----
__global__ __launch_bounds__(1024) void scan1(const int* __restrict__ cnt, int* __restrict__ off,
                                              int* __restrict__ bsum, int n) {
    __shared__ int wsum[16];
    const int lane = threadIdx.x & 63;
    const int wid = threadIdx.x >> 6;
    int i = blockIdx.x * 1024 + threadIdx.x;
    int v = (i < n) ? cnt[i] : 0;
    int s = v;
    #pragma unroll
    for (int o = 1; o < 64; o <<= 1) {
        int t = __shfl_up(s, o, 64);
        if (lane >= o) s += t;
    }
    if (lane == 63) wsum[wid] = s;
    __syncthreads();
    if (wid == 0 && lane < 16) {
        int t = wsum[lane];
        #pragma unroll
        for (int o = 1; o < 16; o <<= 1) {
            int u = __shfl_up(t, o, 64);
            if (lane >= o) t += u;
        }
        wsum[lane] = t;
    }
    __syncthreads();
    int woff = (wid > 0) ? wsum[wid - 1] : 0;
    if (i < n) off[i] = woff + s - v;
    if (threadIdx.x == 0) bsum[blockIdx.x] = wsum[15];
}

__global__ __launch_bounds__(128) void scan2(const int* __restrict__ bsum, int* __restrict__ bbase,
                                             int nb, int* __restrict__ off_end, float* __restrict__ acc) {
    __shared__ int w0tot;
    int tid = threadIdx.x;
    int lane = tid & 63;
    int wid = tid >> 6;
    int v = (tid < nb) ? bsum[tid] : 0;
    int s = v;
    #pragma unroll
    for (int o = 1; o < 64; o <<= 1) {
        int t = __shfl_up(s, o, 64);
        if (lane >= o) s += t;
    }
    if (wid == 0 && lane == 63) w0tot = s;
    __syncthreads();
    int base = (wid == 1) ? w0tot : 0;
    if (tid < nb) bbase[tid] = base + s - v;
    if (tid == nb - 1) *off_end = base + s;
    if (tid == 0) *acc = 0.f;
}

__global__ __launch_bounds__(256) void scan3(int* __restrict__ off, const int* __restrict__ bbase, int n) {
    int i = blockIdx.x * 256 + threadIdx.x;
    int st = gridDim.x * 256;
    for (; i < n; i += st) off[i] += bbase[i >> 10];
}

// ================= partitioned CSR fill (LDS cursors, no global atomics) =================
__global__ __launch_bounds__(1024) void fill_part(
    const int* __restrict__ s1, const int* __restrict__ d1,
    const int* __restrict__ s2, const int* __restrict__ d2,
    const int* __restrict__ s3, const int* __restrict__ d3,
    const float* __restrict__ w1, const float* __restrict__ w2, const float* __restrict__ w3,
    int E1, int E2, int E3, int n1, int n2, int NT,
    const int* __restrict__ off, int2* __restrict__ csr) {
    __shared__ int curs[HBINS];
    const int base = blockIdx.x * HBINS;
    for (int i = threadIdx.x; i < HBINS; i += 1024) {
        int g = base + i;
        curs[i] = (g < NT) ? off[g] : 0;
    }
    __syncthreads();
    {   // segment 1
        int n4 = E1 >> 2;
        const int4* dd = (const int4*)d1;
        for (int i = threadIdx.x; i < n4; i += 1024) {
            int4 v = dd[i];
            int dv[4] = {v.x, v.y, v.z, v.w};
            #pragma unroll
            for (int u = 0; u < 4; ++u) {
                int r = dv[u] - base;
                if ((uint)r < HBINS) {
                    int p = atomicAdd(&curs[r], 1);
                    csr[p] = make_int2(s1[i * 4 + u], __float_as_int(w1[i * 4 + u]));
                }
            }
        }
        for (int i = n4 * 4 + threadIdx.x; i < E1; i += 1024) {
            int r = d1[i] - base;
            if ((uint)r < HBINS) {
                int p = atomicAdd(&curs[r], 1);
                csr[p] = make_int2(s1[i], __float_as_int(w1[i]));
            }
        }
    }
    {   // segment 2
        int n4 = E2 >> 2;
        const int4* dd = (const int4*)d2;
        for (int i = threadIdx.x; i < n4; i += 1024) {
            int4 v = dd[i];
            int dv[4] = {v.x, v.y, v.z, v.w};
            #pragma unroll
            for (int u = 0; u < 4; ++u) {
                int r = n1 + dv[u] - base;
                if ((uint)r < HBINS) {
                    int p = atomicAdd(&curs[r], 1);
                    csr[p] = make_int2(s2[i * 4 + u], __float_as_int(w2[i * 4 + u]));
                }
            }
        }
        for (int i = n4 * 4 + threadIdx.x; i < E2; i += 1024) {
            int r = n1 + d2[i] - base;
            if ((uint)r < HBINS) {
                int p = atomicAdd(&curs[r], 1);
                csr[p] = make_int2(s2[i], __float_as_int(w2[i]));
            }
        }
    }
    {   // segment 3
        int n4 = E3 >> 2;
        const int4* dd = (const int4*)d3;
        for (int i = threadIdx.x; i < n4; i += 1024) {
            int4 v = dd[i];
            int dv[4] = {v.x, v.y, v.z, v.w};
            #pragma unroll
            for (int u = 0; u < 4; ++u) {
                int r = n1 + n2 + dv[u] - base;
                if ((uint)r < HBINS) {
                    int p = atomicAdd(&curs[r], 1);
                    csr[p] = make_int2(s3[i * 4 + u], __float_as_int(w3[i * 4 + u]));
                }
            }
        }
        for (int i = n4 * 4 + threadIdx.x; i < E3; i += 1024) {
            int r = n1 + n2 + d3[i] - base;
            if ((uint)r < HBINS) {
                int p = atomicAdd(&curs[r], 1);
                csr[p] = make_int2(s3[i], __float_as_int(w3[i]));
            }
        }
    }
}

// ================= gather, bf16 in/out, F == 256, shuffle-broadcast + 8x ILP =================
__global__ __launch_bounds__(256) void gather_b4(const ushort* __restrict__ hb,
                                                 const int* __restrict__ off,
                                                 const int2* __restrict__ csr,
                                                 ushort* __restrict__ out, int n_dst) {
    int d = blockIdx.x * 4 + (threadIdx.x >> 6);
    if (d >= n_dst) return;
    int lane = threadIdx.x & 63;
    int i0 = off[d], i1 = off[d + 1];
    float a0 = 0.f, a1 = 0.f, a2 = 0.f, a3 = 0.f;
    for (int base = i0; base < i1; base += 64) {
        int cnt = i1 - base;
        if (cnt > 64) cnt = 64;
        int2 e = csr[base + (lane < cnt ? lane : 0)];
        int j = 0;
        for (; j + 8 <= cnt; j += 8) {
            int s[8]; float wv[8];
            #pragma unroll
            for (int u = 0; u < 8; ++u) {
                s[u] = __shfl(e.x, j + u, 64);
                wv[u] = __int_as_float(__shfl(e.y, j + u, 64));
            }
            ushort4 v[8];
            #pragma unroll
            for (int u = 0; u < 8; ++u)
                v[u] = *reinterpret_cast<const ushort4*>(&hb[(long)s[u] * 256 + lane * 4]);
            #pragma unroll
            for (int u = 0; u < 8; ++u) {
                a0 += wv[u] * b2f(v[u].x);
                a1 += wv[u] * b2f(v[u].y);
                a2 += wv[u] * b2f(v[u].z);
                a3 += wv[u] * b2f(v[u].w);
            }
        }
        for (; j < cnt; ++j) {
            int sv = __shfl(e.x, j, 64);
            float wv = __int_as_float(__shfl(e.y, j, 64));
            ushort4 v = *reinterpret_cast<const ushort4*>(&hb[(long)sv * 256 + lane * 4]);
            a0 += wv * b2f(v.x); a1 += wv * b2f(v.y); a2 += wv * b2f(v.z); a3 += wv * b2f(v.w);
        }
    }
    ushort4 o;
    o.x = f2b(a0); o.y = f2b(a1); o.z = f2b(a2); o.w = f2b(a3);
    *reinterpret_cast<ushort4*>(&out[(long)d * 256 + lane * 4]) = o;
}

// ================= gather, small F (<=64), f32, 4x ILP =================
__global__ __launch_bounds__(256) void gather_small(const float* __restrict__ h,
                                                    const int* __restrict__ off,
                                                    const int2* __restrict__ csr,
                                                    float* __restrict__ y, int n_dst, int F) {
    int d = blockIdx.x * 4 + (threadIdx.x >> 6);
    if (d >= n_dst) return;
    int lane = threadIdx.x & 63;
    int i0 = off[d], i1 = off[d + 1];
    float acc = 0.f;
    for (int base = i0; base < i1; base += 64) {
        int cnt = i1 - base;
        if (cnt > 64) cnt = 64;
        int2 e = csr[base + (lane < cnt ? lane : 0)];
        int j = 0;
        for (; j + 4 <= cnt; j += 4) {
            int s[4]; float wv[4];
            #pragma unroll
            for (int u = 0; u < 4; ++u) {
                s[u] = __shfl(e.x, j + u, 64);
                wv[u] = __int_as_float(__shfl(e.y, j + u, 64));
            }
            float v[4];
            #pragma unroll
            for (int u = 0; u < 4; ++u) v[u] = (lane < F) ? h[(long)s[u] * F + lane] : 0.f;
            #pragma unroll
            for (int u = 0; u < 4; ++u) acc += wv[u] * v[u];
        }
        for (; j < cnt; ++j) {
            int sv = __shfl(e.x, j, 64);
            float wv = __int_as_float(__shfl(e.y, j, 64));
            if (lane < F) acc += wv * h[(long)sv * F + lane];
        }
    }
    if (lane < F) y[(long)d * F + lane] = acc;
}

// ================= bf16 MFMA GEMM: C = act(A @ Bt^T + rowsc⊗bias) =================
template <bool RELU, bool OUTF32, bool ROWSC, bool GUARDN>
__global__ __launch_bounds__(256) void gemm_mfma(const ushort* __restrict__ A,
                                                 const ushort* __restrict__ Bt,
                                                 const float* __restrict__ bias,
                                                 const float* __restrict__ rowsc,
                                                 ushort* __restrict__ Cb,
                                                 float* __restrict__ Cf,
                                                 int M, int Nout, int K) {
    __shared__ ushort As[4096];
    __shared__ ushort Bs[4096];
    const int tid = threadIdx.x;
    const int w = tid >> 6;
    const int lane = tid & 63;
    const int l15 = lane & 15;
    const int l4 = lane >> 4;
    const int bm = blockIdx.x * 128;
    const int bn = blockIdx.y * 128;
    const int wm = w >> 1, wn = w & 1;

    int ra0 = bm + w * 16 + l15;       if (ra0 >= M) ra0 = M - 1;
    int ra1 = bm + (w + 4) * 16 + l15; if (ra1 >= M) ra1 = M - 1;
    const ushort* pa0 = A + (long)ra0 * K + l4 * 8;
    const ushort* pa1 = A + (long)ra1 * K + l4 * 8;
    const ushort* pb0 = Bt + (long)(bn + w * 16 + l15) * K + l4 * 8;
    const ushort* pb1 = Bt + (long)(bn + (w + 4) * 16 + l15) * K + l4 * 8;

    f32x4 acc[4][4];
    f32x4 zz = {0.f, 0.f, 0.f, 0.f};
    #pragma unroll
    for (int m = 0; m < 4; ++m)
        #pragma unroll
        for (int n = 0; n < 4; ++n) acc[m][n] = zz;

    for (int k0 = 0; k0 < K; k0 += 32) {
        __builtin_amdgcn_global_load_lds((const __attribute__((address_space(1))) void*)pa0,
                                         (__attribute__((address_space(3))) void*)&As[w * 512], 16, 0, 0);
        __builtin_amdgcn_global_load_lds((const __attribute__((address_space(1))) void*)pa1,
                                         (__attribute__((address_space(3))) void*)&As[(w + 4) * 512], 16, 0, 0);
        __builtin_amdgcn_global_load_lds((const __attribute__((address_space(1))) void*)pb0,
                                         (__attribute__((address_space(3))) void*)&Bs[w * 512], 16, 0, 0);
        __builtin_amdgcn_global_load_lds((const __attribute__((address_space(1))) void*)pb1,
                                         (__attribute__((address_space(3))) void*)&Bs[(w + 4) * 512], 16, 0, 0);
        pa0 += 32; pa1 += 32; pb0 += 32; pb1 += 32;
        __syncthreads();
        bf16x8 af[4], bfr[4];
        #pragma unroll
        for (int m = 0; m < 4; ++m)
            af[m] = *reinterpret_cast<const bf16x8*>(&As[(wm * 4 + m) * 512 + lane * 8]);
        #pragma unroll
        for (int n = 0; n < 4; ++n)
            bfr[n] = *reinterpret_cast<const bf16x8*>(&Bs[(wn * 4 + n) * 512 + lane * 8]);
        #pragma unroll
        for (int m = 0; m < 4; ++m)
            #pragma unroll
            for (int n = 0; n < 4; ++n)
                acc[m][n] = __builtin_amdgcn_mfma_f32_16x16x32_bf16(af[m], bfr[n], acc[m][n], 0, 0, 0);
        __syncthreads();
    }

    const int rbase = bm + wm * 64;
    const int cbase = bn + wn * 64;
    #pragma unroll
    for (int m = 0; m < 4; ++m) {
        #pragma unroll
        for (int q = 0; q < 4; ++q) {
            int r = rbase + m * 16 + l4 * 4 + q;
            if (r >= M) continue;
            float rs = ROWSC ? rowsc[r] : 1.f;
            #pragma unroll
            for (int n = 0; n < 4; ++n) {
                int c = cbase + n * 16 + l15;
                float v = acc[m][n][q] + rs * bias[c];
                if (RELU) v = fmaxf(v, 0.f);
                if (!GUARDN || c < Nout) {
                    if (OUTF32) Cf[(long)r * Nout + c] = v;
                    else Cb[(long)r * Nout + c] = f2b(v);
                }
            }
        }
    }
}

// ================= column mean =================
__global__ __launch_bounds__(256) void col_mean(const float* __restrict__ y,
                                                float* __restrict__ mean_x,
                                                int rows, int cols) {
    int j = blockIdx.x;
    float s = 0.f;
    for (int i = threadIdx.x; i < rows; i += blockDim.x) s += y[(long)i * cols + j];
    __shared__ float red[256];
    red[threadIdx.x] = s;
    __syncthreads();
    for (int o = 128; o > 0; o >>= 1) {
        if (threadIdx.x < o) red[threadIdx.x] += red[threadIdx.x + o];
        __syncthreads();
    }
    if (threadIdx.x == 0) mean_x[j] = red[0] / (float)rows;
}

// ================= reg loss =================
__global__ __launch_bounds__(256) void reg_loss_k(const float* __restrict__ h,
                                                  const float* __restrict__ u_sum,
                                                  const float* __restrict__ mean_x,
                                                  float* __restrict__ acc,
                                                  int rows, int cols, float inv_n3) {
    long total = (long)rows * cols;
    long idx = (long)blockIdx.x * blockDim.x + threadIdx.x;
    long stride = (long)gridDim.x * blockDim.x;
    float s = 0.f;
    for (long t = idx; t < total; t += stride) {
        int i = (int)(t / cols);
        int j = (int)(t - (long)i * cols);
        float mu = u_sum[i] * inv_n3;
        float d = mu * h[t] - mean_x[j];
        s += d * d;
    }
    __shared__ float red[256];
    red[threadIdx.x] = s;
    __syncthreads();
    for (int o = 128; o > 0; o >>= 1) {
        if (threadIdx.x < o) red[threadIdx.x] += red[threadIdx.x + o];
        __syncthreads();
    }
    if (threadIdx.x == 0) atomicAdd(acc, red[0]);
}

__global__ void finalize_k(float* __restrict__ out, const float* __restrict__ acc, float scale) {
    if (threadIdx.x == 0) *out = *acc * scale;
}

extern "C" void kernel_launch(void* const* d_in, const int* in_sizes, int n_in,
                              void* d_out, int out_size, void* d_ws, size_t ws_size,
                              hipStream_t stream) {
    const float* x   = (const float*)d_in[0];
    const float* W1  = (const float*)d_in[1];
    const float* b1  = (const float*)d_in[2];
    const float* W2  = (const float*)d_in[3];
    const float* b2  = (const float*)d_in[4];
    const float* W3  = (const float*)d_in[5];
    const float* b3  = (const float*)d_in[6];
    const float* ew1 = (const float*)d_in[7];
    const float* ew2 = (const float*)d_in[8];
    const float* ew3 = (const float*)d_in[9];
    const float* u_sum = (const float*)d_in[10];
    const int* s1 = (const int*)d_in[11];
    const int* d1 = (const int*)d_in[12];
    const int* s2 = (const int*)d_in[13];
    const int* d2 = (const int*)d_in[14];
    const int* s3 = (const int*)d_in[15];
    const int* d3 = (const int*)d_in[16];

    const int K  = 256;
    const int n0 = in_sizes[0] / K;          // 100000
    const int E1 = in_sizes[7];              // 800000
    const int E2 = in_sizes[8];              // 400000
    const int E3 = in_sizes[9];              // 200000
    const int n2 = in_sizes[10];             // 25000
    const int NC = in_sizes[5] / K;          // 47
    const int n3 = (out_size - 1) / NC;      // 12500
    const int n1 = 50000;                    // fixed by problem

    const int NT = n1 + n2 + n3;
    const int Et = E1 + E2 + E3;
    const int nb = (NT + 1023) / 1024;
    const int NB = (NT + HBINS - 1) / HBINS;
    const int Gf2b = 1024;

    // ---- workspace layout ----
    float* ws = (float*)d_ws;
    long o = 0;
    auto take = [&](long words) { float* p = ws + o; o += (words + 3) & ~3L; return p; };
    int*    off  = (int*)take(NT + 1);
    int*    cnt  = (int*)take(NT);
    float*  rw   = take(n1 + n2);
    int*    bsum = (int*)take(nb);
    int*    bbase= (int*)take(nb);
    int2*   csr  = (int2*)take(2L * Et);
    ushort* Wt1b = (ushort*)take(256 * 256 / 2);
    ushort* Wt2b = (ushort*)take(256 * 256 / 2);
    ushort* Wt3b = (ushort*)take(128 * 256 / 2);
    float*  b3p  = take(128);
    ushort* aggb = (ushort*)take((long)n1 * 256 / 2);
    ushort* xb   = (ushort*)take((long)n0 * 256 / 2);
    float*  h3   = take((long)n2 * NC);
    float*  mean_x = take(64);
    float*  accs   = take(4);

    ushort* y1b = xb;                           // xb dead after gather1
    ushort* y2b = xb + (long)n1 * 256;
    float*  rw1 = rw;
    float*  rw2 = rw + n1;

    float* y3   = (float*)d_out;
    float* loss = y3 + (long)n3 * NC;

    dim3 blk(256);

    // ---- fused prep: f2b | wtrans | hist ----
    prep_k<<<dim3(Gf2b + 256 + NB), dim3(1024), 0, stream>>>(
        x, xb, (long)n0 * 256 / 8,
        W1, W2, W3, b3, Wt1b, Wt2b, Wt3b, b3p, NC,
        d1, d2, d3, ew1, ew2, E1, E2, E3, n1, n2, NT, cnt, rw, Gf2b);

    // ---- scan + fill ----
    scan1<<<dim3(nb), dim3(1024), 0, stream>>>(cnt, off, bsum, NT);
    scan2<<<dim3(1), dim3(128), 0, stream>>>(bsum, bbase, nb, &off[NT], accs);
    scan3<<<dim3(128), blk, 0, stream>>>(off, bbase, NT);
    fill_part<<<dim3(NB), dim3(1024), 0, stream>>>(s1, d1, s2, d2, s3, d3, ew1, ew2, ew3,
                                                   E1, E2, E3, n1, n2, NT, off, csr);

    // ---- layer 1 ----
    gather_b4<<<dim3((n1 + 3) / 4), blk, 0, stream>>>(xb, off, csr, aggb, n1);
    gemm_mfma<true, false, true, false><<<dim3((n1 + 127) / 128, 2), blk, 0, stream>>>(
        aggb, Wt1b, b1, rw1, y1b, nullptr, n1, 256, K);

    // ---- layer 2 ----
    gather_b4<<<dim3((n2 + 3) / 4), blk, 0, stream>>>(y1b, off + n1, csr, aggb, n2);
    gemm_mfma<true, false, true, false><<<dim3((n2 + 127) / 128, 2), blk, 0, stream>>>(
        aggb, Wt2b, b2, rw2, y2b, n2 ? nullptr : nullptr, n2, 256, K);

    // ---- layer 3 ----
    gemm_mfma<false, true, false, true><<<dim3((n2 + 127) / 128, 1), blk, 0, stream>>>(
        y2b, Wt3b, b3p, nullptr, nullptr, h3, n2, NC, K);
    gather_small<<<dim3((n3 + 3) / 4), blk, 0, stream>>>(h3, off + n1 + n2, csr, y3, n3, NC);

    // ---- reg loss ----
    col_mean<<<dim3(NC), blk, 0, stream>>>(y3, mean_x, n3, NC);
    reg_loss_k<<<dim3(512), blk, 0, stream>>>(h3, u_sum, mean_x, accs, n2, NC, 1.0f / (float)n3);
    finalize_k<<<dim3(1), dim3(1), 0, stream>>>(loss, accs, 1.0f / ((float)n2 * (float)NC));
}

// Round 6
// 347.290 us; speedup vs baseline: 2.9228x; 2.9228x over previous
//
#include <hip/hip_runtime.h>

typedef unsigned int uint;
typedef __attribute__((ext_vector_type(8))) short bf16x8;
typedef __attribute__((ext_vector_type(4))) float f32x4;

__device__ __forceinline__ float b2f(ushort h) { return __uint_as_float(((uint)h) << 16); }
__device__ __forceinline__ ushort f2b(float f) {
    uint u = __float_as_uint(f);
    return (ushort)((u + 0x7fffu + ((u >> 16) & 1u)) >> 16);
}

// ================= zero =================
__global__ __launch_bounds__(256) void zero_i(int* __restrict__ p, int n) {
    int i = blockIdx.x * 256 + threadIdx.x;
    int st = gridDim.x * 256;
    for (; i < n; i += st) p[i] = 0;
}

// ================= fused prep: f2b(x) | wtrans | slot pass (1 atomic/edge) =================
// grid: [0,Gf2b) f2b ; [Gf2b,Gf2b+256) wtrans ; rest: slot pass
__global__ __launch_bounds__(1024) void prep_k(
    const float* __restrict__ x, ushort* __restrict__ xb, long n8,
    const float* __restrict__ W1, const float* __restrict__ W2,
    const float* __restrict__ W3, const float* __restrict__ b3,
    ushort* __restrict__ Wt1, ushort* __restrict__ Wt2,
    ushort* __restrict__ Wt3, float* __restrict__ b3p, int NC,
    const int* __restrict__ d1, const int* __restrict__ d2, const int* __restrict__ d3,
    int E1, int E2, int E3, int n1, int n2,
    int* __restrict__ cnt, int* __restrict__ slot, int Gf2b, int NSLOT) {
    int b = blockIdx.x;
    if (b < Gf2b) {
        long i = (long)b * 1024 + threadIdx.x;
        long st = (long)Gf2b * 1024;
        for (; i < n8; i += st) {
            float4 a = reinterpret_cast<const float4*>(x)[i * 2];
            float4 c = reinterpret_cast<const float4*>(x)[i * 2 + 1];
            ushort4 o0, o1;
            o0.x = f2b(a.x); o0.y = f2b(a.y); o0.z = f2b(a.z); o0.w = f2b(a.w);
            o1.x = f2b(c.x); o1.y = f2b(c.y); o1.z = f2b(c.z); o1.w = f2b(c.w);
            reinterpret_cast<ushort4*>(xb)[i * 2] = o0;
            reinterpret_cast<ushort4*>(xb)[i * 2 + 1] = o1;
        }
        return;
    }
    b -= Gf2b;
    if (b < 256) {
        int k = b;
        int t = threadIdx.x;
        if (t < 256) {
            Wt1[(long)t * 256 + k] = f2b(W1[(long)k * 256 + t]);
        } else if (t < 512) {
            int n = t - 256;
            Wt2[(long)n * 256 + k] = f2b(W2[(long)k * 256 + n]);
        } else if (t < 640) {
            int n = t - 512;
            float v = (n < NC) ? W3[(long)k * NC + n] : 0.f;
            Wt3[(long)n * 256 + k] = f2b(v);
            if (k == 0) b3p[n] = (n < NC) ? b3[n] : 0.f;
        }
        return;
    }
    b -= 256;
    // ---- slot pass: p = cnt[dst_concat]++ ; slot[i] = p ----
    const int tid0 = b * 1024 + threadIdx.x;
    const int st = NSLOT * 1024;
    {   // seg 1 (offset 0)
        int n4 = E1 >> 2;
        const int4* dd = (const int4*)d1;
        for (int i = tid0; i < n4; i += st) {
            int4 v = dd[i];
            slot[i * 4 + 0] = atomicAdd(&cnt[v.x], 1);
            slot[i * 4 + 1] = atomicAdd(&cnt[v.y], 1);
            slot[i * 4 + 2] = atomicAdd(&cnt[v.z], 1);
            slot[i * 4 + 3] = atomicAdd(&cnt[v.w], 1);
        }
        for (int i = n4 * 4 + tid0; i < E1; i += st) slot[i] = atomicAdd(&cnt[d1[i]], 1);
    }
    {   // seg 2 (offset n1)
        int n4 = E2 >> 2;
        const int4* dd = (const int4*)d2;
        int* sl = slot + E1;
        for (int i = tid0; i < n4; i += st) {
            int4 v = dd[i];
            sl[i * 4 + 0] = atomicAdd(&cnt[n1 + v.x], 1);
            sl[i * 4 + 1] = atomicAdd(&cnt[n1 + v.y], 1);
            sl[i * 4 + 2] = atomicAdd(&cnt[n1 + v.z], 1);
            sl[i * 4 + 3] = atomicAdd(&cnt[n1 + v.w], 1);
        }
        for (int i = n4 * 4 + tid0; i < E2; i += st) sl[i] = atomicAdd(&cnt[n1 + d2[i]], 1);
    }
    {   // seg 3 (offset n1+n2)
        int n4 = E3 >> 2;
        const int4* dd = (const int4*)d3;
        int* sl = slot + E1 + E2;
        int base = n1 + n2;
        for (int i = tid0; i < n4; i += st) {
            int4 v = dd[i];
            sl[i * 4 + 0] = atomicAdd(&cnt[base + v.x], 1);
            sl[i * 4 + 1] = atomicAdd(&cnt[base + v.y], 1);
            sl[i * 4 + 2] = atomicAdd(&cnt[base + v.z], 1);
            sl[i * 4 + 3] = atomicAdd(&cnt[base + v.w], 1);
        }
        for (int i = n4 * 4 + tid0; i < E3; i += st) sl[i] = atomicAdd(&cnt[base + d3[i]], 1);
    }
}

// ---- 3-phase parallel exclusive scan ----
__global__ __launch_bounds__(1024) void scan1(const int* __restrict__ cnt, int* __restrict__ off,
                                              int* __restrict__ bsum, int n) {
    __shared__ int wsum[16];
    const int lane = threadIdx.x & 63;
    const int wid = threadIdx.x >> 6;
    int i = blockIdx.x * 1024 + threadIdx.x;
    int v = (i < n) ? cnt[i] : 0;
    int s = v;
    #pragma unroll
    for (int o = 1; o < 64; o <<= 1) {
        int t = __shfl_up(s, o, 64);
        if (lane >= o) s += t;
    }
    if (lane == 63) wsum[wid] = s;
    __syncthreads();
    if (wid == 0 && lane < 16) {
        int t = wsum[lane];
        #pragma unroll
        for (int o = 1; o < 16; o <<= 1) {
            int u = __shfl_up(t, o, 64);
            if (lane >= o) t += u;
        }
        wsum[lane] = t;
    }
    __syncthreads();
    int woff = (wid > 0) ? wsum[wid - 1] : 0;
    if (i < n) off[i] = woff + s - v;
    if (threadIdx.x == 0) bsum[blockIdx.x] = wsum[15];
}

__global__ __launch_bounds__(128) void scan2(const int* __restrict__ bsum, int* __restrict__ bbase,
                                             int nb, int* __restrict__ off_end, float* __restrict__ acc) {
    __shared__ int w0tot;
    int tid = threadIdx.x;
    int lane = tid & 63;
    int wid = tid >> 6;
    int v = (tid < nb) ? bsum[tid] : 0;
    int s = v;
    #pragma unroll
    for (int o = 1; o < 64; o <<= 1) {
        int t = __shfl_up(s, o, 64);
        if (lane >= o) s += t;
    }
    if (wid == 0 && lane == 63) w0tot = s;
    __syncthreads();
    int base = (wid == 1) ? w0tot : 0;
    if (tid < nb) bbase[tid] = base + s - v;
    if (tid == nb - 1) *off_end = base + s;
    if (tid == 0) *acc = 0.f;
}

__global__ __launch_bounds__(256) void scan3(int* __restrict__ off, const int* __restrict__ bbase, int n) {
    int i = blockIdx.x * 256 + threadIdx.x;
    int st = gridDim.x * 256;
    for (; i < n; i += st) off[i] += bbase[i >> 10];
}

// ================= place pass: csr[off[dst]+slot[i]] = (src, w) — no atomics =================
__global__ __launch_bounds__(256) void place_k(
    const int* __restrict__ s1, const int* __restrict__ d1,
    const int* __restrict__ s2, const int* __restrict__ d2,
    const int* __restrict__ s3, const int* __restrict__ d3,
    const float* __restrict__ w1, const float* __restrict__ w2, const float* __restrict__ w3,
    const int* __restrict__ slot, const int* __restrict__ off,
    int2* __restrict__ csr, int E1, int E2, int E3, int n1, int n2) {
    const int tid0 = blockIdx.x * 256 + threadIdx.x;
    const int st = gridDim.x * 256;
    {   // seg 1
        int n4 = E1 >> 2;
        for (int i = tid0; i < n4; i += st) {
            int4 dv = ((const int4*)d1)[i];
            int4 sv = ((const int4*)s1)[i];
            int4 pv = ((const int4*)slot)[i];
            float4 wv = ((const float4*)w1)[i];
            csr[off[dv.x] + pv.x] = make_int2(sv.x, __float_as_int(wv.x));
            csr[off[dv.y] + pv.y] = make_int2(sv.y, __float_as_int(wv.y));
            csr[off[dv.z] + pv.z] = make_int2(sv.z, __float_as_int(wv.z));
            csr[off[dv.w] + pv.w] = make_int2(sv.w, __float_as_int(wv.w));
        }
        for (int i = n4 * 4 + tid0; i < E1; i += st)
            csr[off[d1[i]] + slot[i]] = make_int2(s1[i], __float_as_int(w1[i]));
    }
    {   // seg 2
        int n4 = E2 >> 2;
        const int* sl = slot + E1;
        for (int i = tid0; i < n4; i += st) {
            int4 dv = ((const int4*)d2)[i];
            int4 sv = ((const int4*)s2)[i];
            int4 pv = ((const int4*)sl)[i];
            float4 wv = ((const float4*)w2)[i];
            csr[off[n1 + dv.x] + pv.x] = make_int2(sv.x, __float_as_int(wv.x));
            csr[off[n1 + dv.y] + pv.y] = make_int2(sv.y, __float_as_int(wv.y));
            csr[off[n1 + dv.z] + pv.z] = make_int2(sv.z, __float_as_int(wv.z));
            csr[off[n1 + dv.w] + pv.w] = make_int2(sv.w, __float_as_int(wv.w));
        }
        for (int i = n4 * 4 + tid0; i < E2; i += st)
            csr[off[n1 + d2[i]] + sl[i]] = make_int2(s2[i], __float_as_int(w2[i]));
    }
    {   // seg 3
        int n4 = E3 >> 2;
        const int* sl = slot + E1 + E2;
        int base = n1 + n2;
        for (int i = tid0; i < n4; i += st) {
            int4 dv = ((const int4*)d3)[i];
            int4 sv = ((const int4*)s3)[i];
            int4 pv = ((const int4*)sl)[i];
            float4 wv = ((const float4*)w3)[i];
            csr[off[base + dv.x] + pv.x] = make_int2(sv.x, __float_as_int(wv.x));
            csr[off[base + dv.y] + pv.y] = make_int2(sv.y, __float_as_int(wv.y));
            csr[off[base + dv.z] + pv.z] = make_int2(sv.z, __float_as_int(wv.z));
            csr[off[base + dv.w] + pv.w] = make_int2(sv.w, __float_as_int(wv.w));
        }
        for (int i = n4 * 4 + tid0; i < E3; i += st)
            csr[off[base + d3[i]] + sl[i]] = make_int2(s3[i], __float_as_int(w3[i]));
    }
}

// ================= gather, bf16, F == 256, shuffle-broadcast + 8x ILP; also writes rw = Σw =================
__global__ __launch_bounds__(256) void gather_b4(const ushort* __restrict__ hb,
                                                 const int* __restrict__ off,
                                                 const int2* __restrict__ csr,
                                                 ushort* __restrict__ out,
                                                 float* __restrict__ rw, int n_dst) {
    int d = blockIdx.x * 4 + (threadIdx.x >> 6);
    if (d >= n_dst) return;
    int lane = threadIdx.x & 63;
    int i0 = off[d], i1 = off[d + 1];
    float a0 = 0.f, a1 = 0.f, a2 = 0.f, a3 = 0.f, sw = 0.f;
    for (int base = i0; base < i1; base += 64) {
        int cnt = i1 - base;
        if (cnt > 64) cnt = 64;
        int2 e = csr[base + (lane < cnt ? lane : 0)];
        int j = 0;
        for (; j + 8 <= cnt; j += 8) {
            int s[8]; float wv[8];
            #pragma unroll
            for (int u = 0; u < 8; ++u) {
                s[u] = __shfl(e.x, j + u, 64);
                wv[u] = __int_as_float(__shfl(e.y, j + u, 64));
            }
            ushort4 v[8];
            #pragma unroll
            for (int u = 0; u < 8; ++u)
                v[u] = *reinterpret_cast<const ushort4*>(&hb[(long)s[u] * 256 + lane * 4]);
            #pragma unroll
            for (int u = 0; u < 8; ++u) {
                a0 += wv[u] * b2f(v[u].x);
                a1 += wv[u] * b2f(v[u].y);
                a2 += wv[u] * b2f(v[u].z);
                a3 += wv[u] * b2f(v[u].w);
                sw += wv[u];
            }
        }
        for (; j < cnt; ++j) {
            int sv = __shfl(e.x, j, 64);
            float wv = __int_as_float(__shfl(e.y, j, 64));
            ushort4 v = *reinterpret_cast<const ushort4*>(&hb[(long)sv * 256 + lane * 4]);
            a0 += wv * b2f(v.x); a1 += wv * b2f(v.y); a2 += wv * b2f(v.z); a3 += wv * b2f(v.w);
            sw += wv;
        }
    }
    ushort4 o;
    o.x = f2b(a0); o.y = f2b(a1); o.z = f2b(a2); o.w = f2b(a3);
    *reinterpret_cast<ushort4*>(&out[(long)d * 256 + lane * 4]) = o;
    if (lane == 0) rw[d] = sw;
}

// ================= gather, small F (<=64), f32, 4x ILP =================
__global__ __launch_bounds__(256) void gather_small(const float* __restrict__ h,
                                                    const int* __restrict__ off,
                                                    const int2* __restrict__ csr,
                                                    float* __restrict__ y, int n_dst, int F) {
    int d = blockIdx.x * 4 + (threadIdx.x >> 6);
    if (d >= n_dst) return;
    int lane = threadIdx.x & 63;
    int i0 = off[d], i1 = off[d + 1];
    float acc = 0.f;
    for (int base = i0; base < i1; base += 64) {
        int cnt = i1 - base;
        if (cnt > 64) cnt = 64;
        int2 e = csr[base + (lane < cnt ? lane : 0)];
        int j = 0;
        for (; j + 4 <= cnt; j += 4) {
            int s[4]; float wv[4];
            #pragma unroll
            for (int u = 0; u < 4; ++u) {
                s[u] = __shfl(e.x, j + u, 64);
                wv[u] = __int_as_float(__shfl(e.y, j + u, 64));
            }
            float v[4];
            #pragma unroll
            for (int u = 0; u < 4; ++u) v[u] = (lane < F) ? h[(long)s[u] * F + lane] : 0.f;
            #pragma unroll
            for (int u = 0; u < 4; ++u) acc += wv[u] * v[u];
        }
        for (; j < cnt; ++j) {
            int sv = __shfl(e.x, j, 64);
            float wv = __int_as_float(__shfl(e.y, j, 64));
            if (lane < F) acc += wv * h[(long)sv * F + lane];
        }
    }
    if (lane < F) y[(long)d * F + lane] = acc;
}

// ================= bf16 MFMA GEMM: C = act(A @ Bt^T + rowsc⊗bias) =================
template <bool RELU, bool OUTF32, bool ROWSC, bool GUARDN>
__global__ __launch_bounds__(256) void gemm_mfma(const ushort* __restrict__ A,
                                                 const ushort* __restrict__ Bt,
                                                 const float* __restrict__ bias,
                                                 const float* __restrict__ rowsc,
                                                 ushort* __restrict__ Cb,
                                                 float* __restrict__ Cf,
                                                 int M, int Nout, int K) {
    __shared__ ushort As[4096];
    __shared__ ushort Bs[4096];
    const int tid = threadIdx.x;
    const int w = tid >> 6;
    const int lane = tid & 63;
    const int l15 = lane & 15;
    const int l4 = lane >> 4;
    const int bm = blockIdx.x * 128;
    const int bn = blockIdx.y * 128;
    const int wm = w >> 1, wn = w & 1;

    int ra0 = bm + w * 16 + l15;       if (ra0 >= M) ra0 = M - 1;
    int ra1 = bm + (w + 4) * 16 + l15; if (ra1 >= M) ra1 = M - 1;
    const ushort* pa0 = A + (long)ra0 * K + l4 * 8;
    const ushort* pa1 = A + (long)ra1 * K + l4 * 8;
    const ushort* pb0 = Bt + (long)(bn + w * 16 + l15) * K + l4 * 8;
    const ushort* pb1 = Bt + (long)(bn + (w + 4) * 16 + l15) * K + l4 * 8;

    f32x4 acc[4][4];
    f32x4 zz = {0.f, 0.f, 0.f, 0.f};
    #pragma unroll
    for (int m = 0; m < 4; ++m)
        #pragma unroll
        for (int n = 0; n < 4; ++n) acc[m][n] = zz;

    for (int k0 = 0; k0 < K; k0 += 32) {
        __builtin_amdgcn_global_load_lds((const __attribute__((address_space(1))) void*)pa0,
                                         (__attribute__((address_space(3))) void*)&As[w * 512], 16, 0, 0);
        __builtin_amdgcn_global_load_lds((const __attribute__((address_space(1))) void*)pa1,
                                         (__attribute__((address_space(3))) void*)&As[(w + 4) * 512], 16, 0, 0);
        __builtin_amdgcn_global_load_lds((const __attribute__((address_space(1))) void*)pb0,
                                         (__attribute__((address_space(3))) void*)&Bs[w * 512], 16, 0, 0);
        __builtin_amdgcn_global_load_lds((const __attribute__((address_space(1))) void*)pb1,
                                         (__attribute__((address_space(3))) void*)&Bs[(w + 4) * 512], 16, 0, 0);
        pa0 += 32; pa1 += 32; pb0 += 32; pb1 += 32;
        __syncthreads();
        bf16x8 af[4], bfr[4];
        #pragma unroll
        for (int m = 0; m < 4; ++m)
            af[m] = *reinterpret_cast<const bf16x8*>(&As[(wm * 4 + m) * 512 + lane * 8]);
        #pragma unroll
        for (int n = 0; n < 4; ++n)
            bfr[n] = *reinterpret_cast<const bf16x8*>(&Bs[(wn * 4 + n) * 512 + lane * 8]);
        #pragma unroll
        for (int m = 0; m < 4; ++m)
            #pragma unroll
            for (int n = 0; n < 4; ++n)
                acc[m][n] = __builtin_amdgcn_mfma_f32_16x16x32_bf16(af[m], bfr[n], acc[m][n], 0, 0, 0);
        __syncthreads();
    }

    const int rbase = bm + wm * 64;
    const int cbase = bn + wn * 64;
    #pragma unroll
    for (int m = 0; m < 4; ++m) {
        #pragma unroll
        for (int q = 0; q < 4; ++q) {
            int r = rbase + m * 16 + l4 * 4 + q;
            if (r >= M) continue;
            float rs = ROWSC ? rowsc[r] : 1.f;
            #pragma unroll
            for (int n = 0; n < 4; ++n) {
                int c = cbase + n * 16 + l15;
                float v = acc[m][n][q] + rs * bias[c];
                if (RELU) v = fmaxf(v, 0.f);
                if (!GUARDN || c < Nout) {
                    if (OUTF32) Cf[(long)r * Nout + c] = v;
                    else Cb[(long)r * Nout + c] = f2b(v);
                }
            }
        }
    }
}

// ================= column mean =================
__global__ __launch_bounds__(256) void col_mean(const float* __restrict__ y,
                                                float* __restrict__ mean_x,
                                                int rows, int cols) {
    int j = blockIdx.x;
    float s = 0.f;
    for (int i = threadIdx.x; i < rows; i += blockDim.x) s += y[(long)i * cols + j];
    __shared__ float red[256];
    red[threadIdx.x] = s;
    __syncthreads();
    for (int o = 128; o > 0; o >>= 1) {
        if (threadIdx.x < o) red[threadIdx.x] += red[threadIdx.x + o];
        __syncthreads();
    }
    if (threadIdx.x == 0) mean_x[j] = red[0] / (float)rows;
}

// ================= reg loss =================
__global__ __launch_bounds__(256) void reg_loss_k(const float* __restrict__ h,
                                                  const float* __restrict__ u_sum,
                                                  const float* __restrict__ mean_x,
                                                  float* __restrict__ acc,
                                                  int rows, int cols, float inv_n3) {
    long total = (long)rows * cols;
    long idx = (long)blockIdx.x * blockDim.x + threadIdx.x;
    long stride = (long)gridDim.x * blockDim.x;
    float s = 0.f;
    for (long t = idx; t < total; t += stride) {
        int i = (int)(t / cols);
        int j = (int)(t - (long)i * cols);
        float mu = u_sum[i] * inv_n3;
        float d = mu * h[t] - mean_x[j];
        s += d * d;
    }
    __shared__ float red[256];
    red[threadIdx.x] = s;
    __syncthreads();
    for (int o = 128; o > 0; o >>= 1) {
        if (threadIdx.x < o) red[threadIdx.x] += red[threadIdx.x + o];
        __syncthreads();
    }
    if (threadIdx.x == 0) atomicAdd(acc, red[0]);
}

__global__ void finalize_k(float* __restrict__ out, const float* __restrict__ acc, float scale) {
    if (threadIdx.x == 0) *out = *acc * scale;
}

extern "C" void kernel_launch(void* const* d_in, const int* in_sizes, int n_in,
                              void* d_out, int out_size, void* d_ws, size_t ws_size,
                              hipStream_t stream) {
    const float* x   = (const float*)d_in[0];
    const float* W1  = (const float*)d_in[1];
    const float* b1  = (const float*)d_in[2];
    const float* W2  = (const float*)d_in[3];
    const float* b2  = (const float*)d_in[4];
    const float* W3  = (const float*)d_in[5];
    const float* b3  = (const float*)d_in[6];
    const float* ew1 = (const float*)d_in[7];
    const float* ew2 = (const float*)d_in[8];
    const float* ew3 = (const float*)d_in[9];
    const float* u_sum = (const float*)d_in[10];
    const int* s1 = (const int*)d_in[11];
    const int* d1 = (const int*)d_in[12];
    const int* s2 = (const int*)d_in[13];
    const int* d2 = (const int*)d_in[14];
    const int* s3 = (const int*)d_in[15];
    const int* d3 = (const int*)d_in[16];

    const int K  = 256;
    const int n0 = in_sizes[0] / K;          // 100000
    const int E1 = in_sizes[7];              // 800000
    const int E2 = in_sizes[8];              // 400000
    const int E3 = in_sizes[9];              // 200000
    const int n2 = in_sizes[10];             // 25000
    const int NC = in_sizes[5] / K;          // 47
    const int n3 = (out_size - 1) / NC;      // 12500
    const int n1 = 50000;                    // fixed by problem

    const int NT = n1 + n2 + n3;
    const int Et = E1 + E2 + E3;
    const int nb = (NT + 1023) / 1024;
    const int Gf2b = 1024;
    const int NSLOT = 2048;

    // ---- workspace layout ----
    float* ws = (float*)d_ws;
    long o = 0;
    auto take = [&](long words) { float* p = ws + o; o += (words + 3) & ~3L; return p; };
    int*    off  = (int*)take(NT + 1);
    int*    cnt  = (int*)take(NT);
    float*  rw   = take(n1 + n2);
    int*    bsum = (int*)take(nb);
    int*    bbase= (int*)take(nb);
    int*    slot = (int*)take(Et);
    int2*   csr  = (int2*)take(2L * Et);
    ushort* Wt1b = (ushort*)take(256 * 256 / 2);
    ushort* Wt2b = (ushort*)take(256 * 256 / 2);
    ushort* Wt3b = (ushort*)take(128 * 256 / 2);
    float*  b3p  = take(128);
    ushort* aggb = (ushort*)take((long)n1 * 256 / 2);
    ushort* xb   = (ushort*)take((long)n0 * 256 / 2);
    float*  h3   = take((long)n2 * NC);
    float*  mean_x = take(64);
    float*  accs   = take(4);

    ushort* y1b = xb;                           // xb dead after gather1
    ushort* y2b = xb + (long)n1 * 256;
    float*  rw1 = rw;
    float*  rw2 = rw + n1;

    float* y3   = (float*)d_out;
    float* loss = y3 + (long)n3 * NC;

    dim3 blk(256);

    // ---- CSR build: zero cnt, then fused prep (f2b | wtrans | slot pass) ----
    zero_i<<<dim3(128), blk, 0, stream>>>(cnt, NT);
    prep_k<<<dim3(Gf2b + 256 + NSLOT), dim3(1024), 0, stream>>>(
        x, xb, (long)n0 * 256 / 8,
        W1, W2, W3, b3, Wt1b, Wt2b, Wt3b, b3p, NC,
        d1, d2, d3, E1, E2, E3, n1, n2, cnt, slot, Gf2b, NSLOT);

    // ---- scan + place ----
    scan1<<<dim3(nb), dim3(1024), 0, stream>>>(cnt, off, bsum, NT);
    scan2<<<dim3(1), dim3(128), 0, stream>>>(bsum, bbase, nb, &off[NT], accs);
    scan3<<<dim3(128), blk, 0, stream>>>(off, bbase, NT);
    place_k<<<dim3(2048), blk, 0, stream>>>(s1, d1, s2, d2, s3, d3, ew1, ew2, ew3,
                                            slot, off, csr, E1, E2, E3, n1, n2);

    // ---- layer 1: agg1 = S1@xb (rw1 = S1 rowsums) ; y1b = relu(agg1@W1 + rw1⊗b1) ----
    gather_b4<<<dim3((n1 + 3) / 4), blk, 0, stream>>>(xb, off, csr, aggb, rw1, n1);
    gemm_mfma<true, false, true, false><<<dim3((n1 + 127) / 128, 2), blk, 0, stream>>>(
        aggb, Wt1b, b1, rw1, y1b, nullptr, n1, 256, K);

    // ---- layer 2 ----
    gather_b4<<<dim3((n2 + 3) / 4), blk, 0, stream>>>(y1b, off + n1, csr, aggb, rw2, n2);
    gemm_mfma<true, false, true, false><<<dim3((n2 + 127) / 128, 2), blk, 0, stream>>>(
        aggb, Wt2b, b2, rw2, y2b, nullptr, n2, 256, K);

    // ---- layer 3 ----
    gemm_mfma<false, true, false, true><<<dim3((n2 + 127) / 128, 1), blk, 0, stream>>>(
        y2b, Wt3b, b3p, nullptr, nullptr, h3, n2, NC, K);
    gather_small<<<dim3((n3 + 3) / 4), blk, 0, stream>>>(h3, off + n1 + n2, csr, y3, n3, NC);

    // ---- reg loss ----
    col_mean<<<dim3(NC), blk, 0, stream>>>(y3, mean_x, n3, NC);
    reg_loss_k<<<dim3(512), blk, 0, stream>>>(h3, u_sum, mean_x, accs, n2, NC, 1.0f / (float)n3);
    finalize_k<<<dim3(1), dim3(1), 0, stream>>>(loss, accs, 1.0f / ((float)n2 * (float)NC));
}

// Round 7
// 295.466 us; speedup vs baseline: 3.4355x; 1.1754x over previous
//
#include <hip/hip_runtime.h>

typedef unsigned int uint;
typedef __attribute__((ext_vector_type(8))) short bf16x8;
typedef __attribute__((ext_vector_type(4))) float f32x4;

__device__ __forceinline__ float b2f(ushort h) { return __uint_as_float(((uint)h) << 16); }
__device__ __forceinline__ ushort f2b(float f) {
    uint u = __float_as_uint(f);
    return (ushort)((u + 0x7fffu + ((u >> 16) & 1u)) >> 16);
}

#define NBLK_S 256   // sort blocks (pass A / pass C)

// ================= fused prep: f2b(x) | wtrans | pass A (LDS bucket hist) =================
// grid: [0,Gf2b) f2b ; [Gf2b,Gf2b+256) wtrans ; [Gf2b+256, +NBLK_S) bucket hist
__global__ __launch_bounds__(1024) void prep_k(
    const float* __restrict__ x, ushort* __restrict__ xb, long n8,
    const float* __restrict__ W1, const float* __restrict__ W2,
    const float* __restrict__ W3, const float* __restrict__ b3,
    ushort* __restrict__ Wt1, ushort* __restrict__ Wt2,
    ushort* __restrict__ Wt3, float* __restrict__ b3p, int NC,
    const int* __restrict__ d1, const int* __restrict__ d2, const int* __restrict__ d3,
    int E1, int E2, int E3, int n1, int n2,
    int* __restrict__ bh, int NBKT, int chunk, int Gf2b) {
    __shared__ int hist[2048];
    int b = blockIdx.x;
    if (b < Gf2b) {
        long i = (long)b * 1024 + threadIdx.x;
        long st = (long)Gf2b * 1024;
        for (; i < n8; i += st) {
            float4 a = reinterpret_cast<const float4*>(x)[i * 2];
            float4 c = reinterpret_cast<const float4*>(x)[i * 2 + 1];
            ushort4 o0, o1;
            o0.x = f2b(a.x); o0.y = f2b(a.y); o0.z = f2b(a.z); o0.w = f2b(a.w);
            o1.x = f2b(c.x); o1.y = f2b(c.y); o1.z = f2b(c.z); o1.w = f2b(c.w);
            reinterpret_cast<ushort4*>(xb)[i * 2] = o0;
            reinterpret_cast<ushort4*>(xb)[i * 2 + 1] = o1;
        }
        return;
    }
    b -= Gf2b;
    if (b < 256) {
        int k = b;
        int t = threadIdx.x;
        if (t < 256) {
            Wt1[(long)t * 256 + k] = f2b(W1[(long)k * 256 + t]);
        } else if (t < 512) {
            int n = t - 256;
            Wt2[(long)n * 256 + k] = f2b(W2[(long)k * 256 + n]);
        } else if (t < 640) {
            int n = t - 512;
            float v = (n < NC) ? W3[(long)k * NC + n] : 0.f;
            Wt3[(long)n * 256 + k] = f2b(v);
            if (k == 0) b3p[n] = (n < NC) ? b3[n] : 0.f;
        }
        return;
    }
    b -= 256;
    // ---- pass A: LDS bucket histogram of this block's contiguous edge chunk ----
    const int Et = E1 + E2 + E3;
    const int c0 = b * chunk;
    const int c1 = (c0 + chunk < Et) ? c0 + chunk : Et;
    for (int i = threadIdx.x; i < NBKT; i += 1024) hist[i] = 0;
    __syncthreads();
    for (int i = c0 + (int)threadIdx.x; i < c1; i += 1024) {
        int g;
        if (i < E1) g = d1[i];
        else if (i < E1 + E2) g = n1 + d2[i - E1];
        else g = n1 + n2 + d3[i - E1 - E2];
        atomicAdd(&hist[g >> 6], 1);
    }
    __syncthreads();
    for (int k = threadIdx.x; k < NBKT; k += 1024) bh[k * NBLK_S + b] = hist[k];
}

// ---- scan phase 1: per-1024-block exclusive scan of bh -> bhs, block sums ----
__global__ __launch_bounds__(1024) void scan1(const int* __restrict__ cnt, int* __restrict__ off,
                                              int* __restrict__ bsum, int n) {
    __shared__ int wsum[16];
    const int lane = threadIdx.x & 63;
    const int wid = threadIdx.x >> 6;
    int i = blockIdx.x * 1024 + threadIdx.x;
    int v = (i < n) ? cnt[i] : 0;
    int s = v;
    #pragma unroll
    for (int o = 1; o < 64; o <<= 1) {
        int t = __shfl_up(s, o, 64);
        if (lane >= o) s += t;
    }
    if (lane == 63) wsum[wid] = s;
    __syncthreads();
    if (wid == 0 && lane < 16) {
        int t = wsum[lane];
        #pragma unroll
        for (int o = 1; o < 16; o <<= 1) {
            int u = __shfl_up(t, o, 64);
            if (lane >= o) t += u;
        }
        wsum[lane] = t;
    }
    __syncthreads();
    int woff = (wid > 0) ? wsum[wid - 1] : 0;
    if (i < n) off[i] = woff + s - v;
    if (threadIdx.x == 0) bsum[blockIdx.x] = wsum[15];
}

// ---- scan phase 2: single block, n <= 1024 block sums; writes off[NT]=total, zeroes acc ----
__global__ __launch_bounds__(1024) void scan2b(const int* __restrict__ bsum, int* __restrict__ bbase,
                                               int n, int* __restrict__ offNT, float* __restrict__ acc) {
    __shared__ int wsum[16];
    int tid = threadIdx.x;
    int lane = tid & 63;
    int wid = tid >> 6;
    int v = (tid < n) ? bsum[tid] : 0;
    int s = v;
    #pragma unroll
    for (int o = 1; o < 64; o <<= 1) {
        int t = __shfl_up(s, o, 64);
        if (lane >= o) s += t;
    }
    if (lane == 63) wsum[wid] = s;
    __syncthreads();
    if (wid == 0 && lane < 16) {
        int t = wsum[lane];
        #pragma unroll
        for (int o = 1; o < 16; o <<= 1) {
            int u = __shfl_up(t, o, 64);
            if (lane >= o) t += u;
        }
        wsum[lane] = t;
    }
    __syncthreads();
    int base = (wid > 0) ? wsum[wid - 1] : 0;
    int excl = base + s - v;
    if (tid < n) bbase[tid] = excl;
    if (tid == n - 1) *offNT = excl + v;
    if (tid == 0) *acc = 0.f;
}

// ---- scan phase 3: add block bases ----
__global__ __launch_bounds__(256) void scan3(int* __restrict__ a, const int* __restrict__ bbase, int n) {
    int i = blockIdx.x * 256 + threadIdx.x;
    int st = gridDim.x * 256;
    for (; i < n; i += st) a[i] += bbase[i >> 10];
}

// ================= pass C: place edges bucket-sorted (LDS cursors only) =================
__global__ __launch_bounds__(1024) void sortC(
    const int* __restrict__ s1, const int* __restrict__ d1,
    const int* __restrict__ s2, const int* __restrict__ d2,
    const int* __restrict__ s3, const int* __restrict__ d3,
    const float* __restrict__ w1, const float* __restrict__ w2, const float* __restrict__ w3,
    const int* __restrict__ bhs, int* __restrict__ bs_g, int2* __restrict__ bs_sw,
    int E1, int E2, int E3, int n1, int n2, int NBKT, int chunk) {
    __shared__ int cur[2048];
    const int b = blockIdx.x;
    const int Et = E1 + E2 + E3;
    const int c0 = b * chunk;
    const int c1 = (c0 + chunk < Et) ? c0 + chunk : Et;
    for (int k = threadIdx.x; k < NBKT; k += 1024) cur[k] = bhs[k * NBLK_S + b];
    __syncthreads();
    for (int i = c0 + (int)threadIdx.x; i < c1; i += 1024) {
        int g, s, w;
        if (i < E1) { g = d1[i]; s = s1[i]; w = __float_as_int(w1[i]); }
        else if (i < E1 + E2) { int j = i - E1; g = n1 + d2[j]; s = s2[j]; w = __float_as_int(w2[j]); }
        else { int j = i - E1 - E2; g = n1 + n2 + d3[j]; s = s3[j]; w = __float_as_int(w3[j]); }
        int p = atomicAdd(&cur[g >> 6], 1);
        bs_g[p] = g;
        bs_sw[p] = make_int2(s, w);
    }
}

// ================= pass D: in-bucket 64-bin counting sort -> final CSR + off =================
__global__ __launch_bounds__(256) void sortD(const int* __restrict__ bhs,
                                             const int* __restrict__ bs_g,
                                             const int2* __restrict__ bs_sw,
                                             int* __restrict__ off, int2* __restrict__ csr,
                                             int NBKT, int NT, int Et) {
    __shared__ int hist[64];
    __shared__ int cur[64];
    const int b = blockIdx.x;
    const int g0 = b << 6;
    const int B0 = bhs[b * NBLK_S];
    const int B1 = (b == NBKT - 1) ? Et : bhs[(b + 1) * NBLK_S];
    const int tid = threadIdx.x;
    if (tid < 64) hist[tid] = 0;
    __syncthreads();
    for (int p = B0 + tid; p < B1; p += 256) atomicAdd(&hist[bs_g[p] - g0], 1);
    __syncthreads();
    if (tid < 64) {
        int v = hist[tid];
        int s = v;
        #pragma unroll
        for (int o = 1; o < 64; o <<= 1) {
            int t = __shfl_up(s, o, 64);
            if (tid >= o) s += t;
        }
        int excl = B0 + s - v;
        cur[tid] = excl;
        int g = g0 + tid;
        if (g < NT) off[g] = excl;
    }
    __syncthreads();
    for (int p = B0 + tid; p < B1; p += 256) {
        int r = bs_g[p] - g0;
        int q = atomicAdd(&cur[r], 1);
        csr[q] = bs_sw[p];
    }
}

// ================= gather, bf16, F == 256, shuffle-broadcast, ILP 8/4; writes rw = Σw =================
__global__ __launch_bounds__(256) void gather_b4(const ushort* __restrict__ hb,
                                                 const int* __restrict__ off,
                                                 const int2* __restrict__ csr,
                                                 ushort* __restrict__ out,
                                                 float* __restrict__ rw, int n_dst) {
    int d = blockIdx.x * 4 + (threadIdx.x >> 6);
    if (d >= n_dst) return;
    int lane = threadIdx.x & 63;
    int i0 = off[d], i1 = off[d + 1];
    float a0 = 0.f, a1 = 0.f, a2 = 0.f, a3 = 0.f, sw = 0.f;
    for (int base = i0; base < i1; base += 64) {
        int cnt = i1 - base;
        if (cnt > 64) cnt = 64;
        int2 e = csr[base + (lane < cnt ? lane : 0)];
        int j = 0;
        for (; j + 8 <= cnt; j += 8) {
            int s[8]; float wv[8];
            #pragma unroll
            for (int u = 0; u < 8; ++u) {
                s[u] = __shfl(e.x, j + u, 64);
                wv[u] = __int_as_float(__shfl(e.y, j + u, 64));
            }
            ushort4 v[8];
            #pragma unroll
            for (int u = 0; u < 8; ++u)
                v[u] = *reinterpret_cast<const ushort4*>(&hb[(long)s[u] * 256 + lane * 4]);
            #pragma unroll
            for (int u = 0; u < 8; ++u) {
                a0 += wv[u] * b2f(v[u].x);
                a1 += wv[u] * b2f(v[u].y);
                a2 += wv[u] * b2f(v[u].z);
                a3 += wv[u] * b2f(v[u].w);
                sw += wv[u];
            }
        }
        for (; j + 4 <= cnt; j += 4) {
            int s[4]; float wv[4];
            #pragma unroll
            for (int u = 0; u < 4; ++u) {
                s[u] = __shfl(e.x, j + u, 64);
                wv[u] = __int_as_float(__shfl(e.y, j + u, 64));
            }
            ushort4 v[4];
            #pragma unroll
            for (int u = 0; u < 4; ++u)
                v[u] = *reinterpret_cast<const ushort4*>(&hb[(long)s[u] * 256 + lane * 4]);
            #pragma unroll
            for (int u = 0; u < 4; ++u) {
                a0 += wv[u] * b2f(v[u].x);
                a1 += wv[u] * b2f(v[u].y);
                a2 += wv[u] * b2f(v[u].z);
                a3 += wv[u] * b2f(v[u].w);
                sw += wv[u];
            }
        }
        for (; j < cnt; ++j) {
            int sv = __shfl(e.x, j, 64);
            float wv = __int_as_float(__shfl(e.y, j, 64));
            ushort4 v = *reinterpret_cast<const ushort4*>(&hb[(long)sv * 256 + lane * 4]);
            a0 += wv * b2f(v.x); a1 += wv * b2f(v.y); a2 += wv * b2f(v.z); a3 += wv * b2f(v.w);
            sw += wv;
        }
    }
    ushort4 o;
    o.x = f2b(a0); o.y = f2b(a1); o.z = f2b(a2); o.w = f2b(a3);
    *reinterpret_cast<ushort4*>(&out[(long)d * 256 + lane * 4]) = o;
    if (lane == 0) rw[d] = sw;
}

// ================= gather, small F (<=64), f32, 4x ILP =================
__global__ __launch_bounds__(256) void gather_small(const float* __restrict__ h,
                                                    const int* __restrict__ off,
                                                    const int2* __restrict__ csr,
                                                    float* __restrict__ y, int n_dst, int F) {
    int d = blockIdx.x * 4 + (threadIdx.x >> 6);
    if (d >= n_dst) return;
    int lane = threadIdx.x & 63;
    int i0 = off[d], i1 = off[d + 1];
    float acc = 0.f;
    for (int base = i0; base < i1; base += 64) {
        int cnt = i1 - base;
        if (cnt > 64) cnt = 64;
        int2 e = csr[base + (lane < cnt ? lane : 0)];
        int j = 0;
        for (; j + 4 <= cnt; j += 4) {
            int s[4]; float wv[4];
            #pragma unroll
            for (int u = 0; u < 4; ++u) {
                s[u] = __shfl(e.x, j + u, 64);
                wv[u] = __int_as_float(__shfl(e.y, j + u, 64));
            }
            float v[4];
            #pragma unroll
            for (int u = 0; u < 4; ++u) v[u] = (lane < F) ? h[(long)s[u] * F + lane] : 0.f;
            #pragma unroll
            for (int u = 0; u < 4; ++u) acc += wv[u] * v[u];
        }
        for (; j < cnt; ++j) {
            int sv = __shfl(e.x, j, 64);
            float wv = __int_as_float(__shfl(e.y, j, 64));
            if (lane < F) acc += wv * h[(long)sv * F + lane];
        }
    }
    if (lane < F) y[(long)d * F + lane] = acc;
}

// ================= bf16 MFMA GEMM: C = act(A @ Bt^T + rowsc⊗bias) =================
template <bool RELU, bool OUTF32, bool ROWSC, bool GUARDN>
__global__ __launch_bounds__(256) void gemm_mfma(const ushort* __restrict__ A,
                                                 const ushort* __restrict__ Bt,
                                                 const float* __restrict__ bias,
                                                 const float* __restrict__ rowsc,
                                                 ushort* __restrict__ Cb,
                                                 float* __restrict__ Cf,
                                                 int M, int Nout, int K) {
    __shared__ ushort As[4096];
    __shared__ ushort Bs[4096];
    const int tid = threadIdx.x;
    const int w = tid >> 6;
    const int lane = tid & 63;
    const int l15 = lane & 15;
    const int l4 = lane >> 4;
    const int bm = blockIdx.x * 128;
    const int bn = blockIdx.y * 128;
    const int wm = w >> 1, wn = w & 1;

    int ra0 = bm + w * 16 + l15;       if (ra0 >= M) ra0 = M - 1;
    int ra1 = bm + (w + 4) * 16 + l15; if (ra1 >= M) ra1 = M - 1;
    const ushort* pa0 = A + (long)ra0 * K + l4 * 8;
    const ushort* pa1 = A + (long)ra1 * K + l4 * 8;
    const ushort* pb0 = Bt + (long)(bn + w * 16 + l15) * K + l4 * 8;
    const ushort* pb1 = Bt + (long)(bn + (w + 4) * 16 + l15) * K + l4 * 8;

    f32x4 acc[4][4];
    f32x4 zz = {0.f, 0.f, 0.f, 0.f};
    #pragma unroll
    for (int m = 0; m < 4; ++m)
        #pragma unroll
        for (int n = 0; n < 4; ++n) acc[m][n] = zz;

    for (int k0 = 0; k0 < K; k0 += 32) {
        __builtin_amdgcn_global_load_lds((const __attribute__((address_space(1))) void*)pa0,
                                         (__attribute__((address_space(3))) void*)&As[w * 512], 16, 0, 0);
        __builtin_amdgcn_global_load_lds((const __attribute__((address_space(1))) void*)pa1,
                                         (__attribute__((address_space(3))) void*)&As[(w + 4) * 512], 16, 0, 0);
        __builtin_amdgcn_global_load_lds((const __attribute__((address_space(1))) void*)pb0,
                                         (__attribute__((address_space(3))) void*)&Bs[w * 512], 16, 0, 0);
        __builtin_amdgcn_global_load_lds((const __attribute__((address_space(1))) void*)pb1,
                                         (__attribute__((address_space(3))) void*)&Bs[(w + 4) * 512], 16, 0, 0);
        pa0 += 32; pa1 += 32; pb0 += 32; pb1 += 32;
        __syncthreads();
        bf16x8 af[4], bfr[4];
        #pragma unroll
        for (int m = 0; m < 4; ++m)
            af[m] = *reinterpret_cast<const bf16x8*>(&As[(wm * 4 + m) * 512 + lane * 8]);
        #pragma unroll
        for (int n = 0; n < 4; ++n)
            bfr[n] = *reinterpret_cast<const bf16x8*>(&Bs[(wn * 4 + n) * 512 + lane * 8]);
        #pragma unroll
        for (int m = 0; m < 4; ++m)
            #pragma unroll
            for (int n = 0; n < 4; ++n)
                acc[m][n] = __builtin_amdgcn_mfma_f32_16x16x32_bf16(af[m], bfr[n], acc[m][n], 0, 0, 0);
        __syncthreads();
    }

    const int rbase = bm + wm * 64;
    const int cbase = bn + wn * 64;
    #pragma unroll
    for (int m = 0; m < 4; ++m) {
        #pragma unroll
        for (int q = 0; q < 4; ++q) {
            int r = rbase + m * 16 + l4 * 4 + q;
            if (r >= M) continue;
            float rs = ROWSC ? rowsc[r] : 1.f;
            #pragma unroll
            for (int n = 0; n < 4; ++n) {
                int c = cbase + n * 16 + l15;
                float v = acc[m][n][q] + rs * bias[c];
                if (RELU) v = fmaxf(v, 0.f);
                if (!GUARDN || c < Nout) {
                    if (OUTF32) Cf[(long)r * Nout + c] = v;
                    else Cb[(long)r * Nout + c] = f2b(v);
                }
            }
        }
    }
}

// ================= column mean =================
__global__ __launch_bounds__(256) void col_mean(const float* __restrict__ y,
                                                float* __restrict__ mean_x,
                                                int rows, int cols) {
    int j = blockIdx.x;
    float s = 0.f;
    for (int i = threadIdx.x; i < rows; i += blockDim.x) s += y[(long)i * cols + j];
    __shared__ float red[256];
    red[threadIdx.x] = s;
    __syncthreads();
    for (int o = 128; o > 0; o >>= 1) {
        if (threadIdx.x < o) red[threadIdx.x] += red[threadIdx.x + o];
        __syncthreads();
    }
    if (threadIdx.x == 0) mean_x[j] = red[0] / (float)rows;
}

// ================= reg loss =================
__global__ __launch_bounds__(256) void reg_loss_k(const float* __restrict__ h,
                                                  const float* __restrict__ u_sum,
                                                  const float* __restrict__ mean_x,
                                                  float* __restrict__ acc,
                                                  int rows, int cols, float inv_n3) {
    long total = (long)rows * cols;
    long idx = (long)blockIdx.x * blockDim.x + threadIdx.x;
    long stride = (long)gridDim.x * blockDim.x;
    float s = 0.f;
    for (long t = idx; t < total; t += stride) {
        int i = (int)(t / cols);
        int j = (int)(t - (long)i * cols);
        float mu = u_sum[i] * inv_n3;
        float d = mu * h[t] - mean_x[j];
        s += d * d;
    }
    __shared__ float red[256];
    red[threadIdx.x] = s;
    __syncthreads();
    for (int o = 128; o > 0; o >>= 1) {
        if (threadIdx.x < o) red[threadIdx.x] += red[threadIdx.x + o];
        __syncthreads();
    }
    if (threadIdx.x == 0) atomicAdd(acc, red[0]);
}

__global__ void finalize_k(float* __restrict__ out, const float* __restrict__ acc, float scale) {
    if (threadIdx.x == 0) *out = *acc * scale;
}

extern "C" void kernel_launch(void* const* d_in, const int* in_sizes, int n_in,
                              void* d_out, int out_size, void* d_ws, size_t ws_size,
                              hipStream_t stream) {
    const float* x   = (const float*)d_in[0];
    const float* W1  = (const float*)d_in[1];
    const float* b1  = (const float*)d_in[2];
    const float* W2  = (const float*)d_in[3];
    const float* b2  = (const float*)d_in[4];
    const float* W3  = (const float*)d_in[5];
    const float* b3  = (const float*)d_in[6];
    const float* ew1 = (const float*)d_in[7];
    const float* ew2 = (const float*)d_in[8];
    const float* ew3 = (const float*)d_in[9];
    const float* u_sum = (const float*)d_in[10];
    const int* s1 = (const int*)d_in[11];
    const int* d1 = (const int*)d_in[12];
    const int* s2 = (const int*)d_in[13];
    const int* d2 = (const int*)d_in[14];
    const int* s3 = (const int*)d_in[15];
    const int* d3 = (const int*)d_in[16];

    const int K  = 256;
    const int n0 = in_sizes[0] / K;          // 100000
    const int E1 = in_sizes[7];              // 800000
    const int E2 = in_sizes[8];              // 400000
    const int E3 = in_sizes[9];              // 200000
    const int n2 = in_sizes[10];             // 25000
    const int NC = in_sizes[5] / K;          // 47
    const int n3 = (out_size - 1) / NC;      // 12500
    const int n1 = 50000;                    // fixed by problem

    const int NT = n1 + n2 + n3;
    const int Et = E1 + E2 + E3;
    const int NBKT = (NT + 63) >> 6;         // coarse buckets of 64 dsts
    const int nscan = NBKT * NBLK_S;
    const int nb = (nscan + 1023) / 1024;
    const int chunk = (Et + NBLK_S - 1) / NBLK_S;
    const int Gf2b = 1024;

    // ---- workspace layout ----
    float* ws = (float*)d_ws;
    long o = 0;
    auto take = [&](long words) { float* p = ws + o; o += (words + 3) & ~3L; return p; };
    int*    off  = (int*)take(NT + 1);
    int*    bh   = (int*)take(nscan);
    int*    bhs  = (int*)take(nscan);
    int*    bsum = (int*)take(nb);
    int*    bbase= (int*)take(nb);
    int*    bs_g = (int*)take(Et);
    int2*   bs_sw= (int2*)take(2L * Et);
    int2*   csr  = (int2*)take(2L * Et);
    float*  rw   = take(n1 + n2);
    ushort* Wt1b = (ushort*)take(256 * 256 / 2);
    ushort* Wt2b = (ushort*)take(256 * 256 / 2);
    ushort* Wt3b = (ushort*)take(128 * 256 / 2);
    float*  b3p  = take(128);
    ushort* aggb = (ushort*)take((long)n1 * 256 / 2);
    ushort* xb   = (ushort*)take((long)n0 * 256 / 2);
    float*  h3   = take((long)n2 * NC);
    float*  mean_x = take(64);
    float*  accs   = take(4);

    ushort* y1b = xb;                           // xb dead after gather1
    ushort* y2b = xb + (long)n1 * 256;
    float*  rw1 = rw;
    float*  rw2 = rw + n1;

    float* y3   = (float*)d_out;
    float* loss = y3 + (long)n3 * NC;

    dim3 blk(256);

    // ---- fused prep: f2b | wtrans | bucket hist (no global atomics anywhere) ----
    prep_k<<<dim3(Gf2b + 256 + NBLK_S), dim3(1024), 0, stream>>>(
        x, xb, (long)n0 * 256 / 8,
        W1, W2, W3, b3, Wt1b, Wt2b, Wt3b, b3p, NC,
        d1, d2, d3, E1, E2, E3, n1, n2, bh, NBKT, chunk, Gf2b);

    // ---- scan bh (bucket-major) ----
    scan1<<<dim3(nb), dim3(1024), 0, stream>>>(bh, bhs, bsum, nscan);
    scan2b<<<dim3(1), dim3(1024), 0, stream>>>(bsum, bbase, nb, &off[NT], accs);
    scan3<<<dim3(256), blk, 0, stream>>>(bhs, bbase, nscan);

    // ---- bucket-sort edges, then in-bucket counting sort -> CSR + off ----
    sortC<<<dim3(NBLK_S), dim3(1024), 0, stream>>>(s1, d1, s2, d2, s3, d3, ew1, ew2, ew3,
                                                   bhs, bs_g, bs_sw, E1, E2, E3, n1, n2, NBKT, chunk);
    sortD<<<dim3(NBKT), blk, 0, stream>>>(bhs, bs_g, bs_sw, off, csr, NBKT, NT, Et);

    // ---- layer 1: agg1 = S1@xb (rw1 = S1 rowsums) ; y1b = relu(agg1@W1 + rw1⊗b1) ----
    gather_b4<<<dim3((n1 + 3) / 4), blk, 0, stream>>>(xb, off, csr, aggb, rw1, n1);
    gemm_mfma<true, false, true, false><<<dim3((n1 + 127) / 128, 2), blk, 0, stream>>>(
        aggb, Wt1b, b1, rw1, y1b, nullptr, n1, 256, K);

    // ---- layer 2 ----
    gather_b4<<<dim3((n2 + 3) / 4), blk, 0, stream>>>(y1b, off + n1, csr, aggb, rw2, n2);
    gemm_mfma<true, false, true, false><<<dim3((n2 + 127) / 128, 2), blk, 0, stream>>>(
        aggb, Wt2b, b2, rw2, y2b, nullptr, n2, 256, K);

    // ---- layer 3 ----
    gemm_mfma<false, true, false, true><<<dim3((n2 + 127) / 128, 1), blk, 0, stream>>>(
        y2b, Wt3b, b3p, nullptr, nullptr, h3, n2, NC, K);
    gather_small<<<dim3((n3 + 3) / 4), blk, 0, stream>>>(h3, off + n1 + n2, csr, y3, n3, NC);

    // ---- reg loss ----
    col_mean<<<dim3(NC), blk, 0, stream>>>(y3, mean_x, n3, NC);
    reg_loss_k<<<dim3(512), blk, 0, stream>>>(h3, u_sum, mean_x, accs, n2, NC, 1.0f / (float)n3);
    finalize_k<<<dim3(1), dim3(1), 0, stream>>>(loss, accs, 1.0f / ((float)n2 * (float)NC));
}